// Round 10
// baseline (224.431 us; speedup 1.0000x reference)
//
#include <hip/hip_runtime.h>
#include <stdint.h>

// Problem constants (fixed shapes from reference)
#define M_DIM 4096   // 2 * 2048 rows of x
#define K_DIM 4096   // in_features
#define N_DIM 4096   // out_features

typedef float f32x4 __attribute__((ext_vector_type(4)));
typedef int   i32x4 __attribute__((ext_vector_type(4)));

// ---------------------------------------------------------------------------
// Quant (R8, unchanged): one WAVE per row, no LDS/syncthreads, coalesced.
// ---------------------------------------------------------------------------
__global__ __launch_bounds__(256) void quant_xw(const float* __restrict__ x,
                                                const int* __restrict__ packed,
                                                const float* __restrict__ d,
                                                const float* __restrict__ dmin,
                                                const int* __restrict__ scales,
                                                const int* __restrict__ mins,
                                                int8_t* __restrict__ xq,
                                                float* __restrict__ sx,
                                                int8_t* __restrict__ wq,
                                                float* __restrict__ sw) {
    const int wave = threadIdx.x >> 6;
    const int lane = threadIdx.x & 63;
    if (blockIdx.x < 1024) {
        const int row = blockIdx.x * 4 + wave;
        const float4* xr = (const float4*)(x + (size_t)row * K_DIM);
        float4 v[16];
#pragma unroll
        for (int c = 0; c < 16; ++c) v[c] = xr[c * 64 + lane];
        float am = 0.f;
#pragma unroll
        for (int c = 0; c < 16; ++c) {
            am = fmaxf(am, fabsf(v[c].x)); am = fmaxf(am, fabsf(v[c].y));
            am = fmaxf(am, fabsf(v[c].z)); am = fmaxf(am, fabsf(v[c].w));
        }
#pragma unroll
        for (int off = 32; off; off >>= 1) am = fmaxf(am, __shfl_xor(am, off, 64));
        am = fmaxf(am, 1e-20f);
        const float inv = 127.0f / am;
        int* oq = (int*)(xq + (size_t)row * K_DIM);
#pragma unroll
        for (int c = 0; c < 16; ++c) {
            int q0 = __float2int_rn(v[c].x * inv);
            int q1 = __float2int_rn(v[c].y * inv);
            int q2 = __float2int_rn(v[c].z * inv);
            int q3 = __float2int_rn(v[c].w * inv);
            oq[c * 64 + lane] = (q0 & 255) | ((q1 & 255) << 8) |
                                ((q2 & 255) << 16) | ((q3 & 255) << 24);
        }
        if (lane == 0) sx[row] = am / 127.0f;
    } else {
        const int n = (blockIdx.x - 1024) * 4 + wave;
        const int sb = n * 128;
        const float s0  = (float)scales[sb + lane];
        const float s1  = (float)scales[sb + 64 + lane];
        const float mn0 = (float)mins[sb + lane];
        const float mn1 = (float)mins[sb + 64 + lane];
        const int di = n * 16;
        const float dd0 = d[di + (lane >> 3)];
        const float dd1 = d[di + 8 + (lane >> 3)];
        const float dm0 = dmin[di + (lane >> 3)];
        const float dm1 = dmin[di + 8 + (lane >> 3)];
        const float a0 = dd0 * s0 * (1.0f / 945.0f);
        const float b0 = dd0 * mn0 * (1.0f / 63.0f) + dm0;
        const float a1 = dd1 * s1 * (1.0f / 945.0f);
        const float b1 = dd1 * mn1 * (1.0f / 63.0f) + dm1;
        float m = fmaxf(15.0f * a0 + b0, 15.0f * a1 + b1);
#pragma unroll
        for (int off = 32; off; off >>= 1) m = fmaxf(m, __shfl_xor(m, off, 64));
        m = fmaxf(m, 1e-20f);
        const float inv = 127.0f / m;
        const float A0 = a0 * inv, B0 = b0 * inv;
        const float A1 = a1 * inv, B1 = b1 * inv;
        const int4* pr = (const int4*)(packed + (size_t)n * (K_DIM / 2));
        int2* outr = (int2*)(wq + (size_t)n * K_DIM);
#pragma unroll
        for (int c = 0; c < 8; ++c) {
            const int4 pv = pr[c * 64 + lane];
            const int sIdx = (c & 3) * 16 + (lane >> 2);
            const float a = (c < 4) ? __shfl(A0, sIdx, 64) : __shfl(A1, sIdx, 64);
            const float b = (c < 4) ? __shfl(B0, sIdx, 64) : __shfl(B1, sIdx, 64);
            int q0 = __float2int_rn((float)(pv.x & 15) * a + b);
            int q1 = __float2int_rn((float)((pv.x >> 4) & 15) * a + b);
            int q2 = __float2int_rn((float)(pv.y & 15) * a + b);
            int q3 = __float2int_rn((float)((pv.y >> 4) & 15) * a + b);
            int q4 = __float2int_rn((float)(pv.z & 15) * a + b);
            int q5 = __float2int_rn((float)((pv.z >> 4) & 15) * a + b);
            int q6 = __float2int_rn((float)(pv.w & 15) * a + b);
            int q7 = __float2int_rn((float)((pv.w >> 4) & 15) * a + b);
            int2 o;
            o.x = (q0 & 255) | ((q1 & 255) << 8) | ((q2 & 255) << 16) | ((q3 & 255) << 24);
            o.y = (q4 & 255) | ((q5 & 255) << 8) | ((q6 & 255) << 16) | ((q7 & 255) << 24);
            outr[c * 64 + lane] = o;
        }
        if (lane == 0) sw[n] = m / 127.0f;
    }
}

// ---------------------------------------------------------------------------
// GEMM R10: the untried matrix cell = {R5-quality schedule} x {2 blocks/CU}.
// 5 schedules at 1 block/CU all hit 71-74 µs (lockstep wall); R6 proved the
// cross-block coverage mechanism engages (VALUBusy 15->45%) but lost to its
// primitive vmcnt(0)-drain schedule. This keeps the R5 pipeline (2 barriers/
// tile, counted WAITV, k-sweep order, weaves at sweep boundaries, proven
// 8-chunk XOR swizzle) on a 128x128 tile / 256 thr / 4 waves (2Mx2N, wave
// tile 64x64) with dbuf LDS = 64 KiB -> 2 blocks/CU: each SIMD hosts one
// wave from EACH block; when block A sits at WAITV/BARRIER, block B issues.
//
// FIFO desk-check (8 loads/wave/tile: B(t+1) x4 then A(t+2) x4):
//   queue at W1(t) = [A(t+1):4, B(t+1):4, A(t+2):4]; WAITV(4) retires
//   A(t+1)+B(t+1) = exactly what region-2's weaves read. Epilogue t=30:
//   queue [A(31):4, B(31):4] -> WAITV(0). Prologue stages A(0),B(0),A(1),
//   WAITV(4) -> A(0),B(0) ready. WAR: every stage overwrites a region whose
//   last LDS read is >=1 barrier back (same discipline as R5, all checked).
// ---------------------------------------------------------------------------
#define BK 128   // bytes of K per K-tile (2 MFMA k-steps of 64)

__device__ __forceinline__ void async_copy16(void* lds, const void* g) {
    __builtin_amdgcn_global_load_lds(
        (const __attribute__((address_space(1))) void*)g,
        (__attribute__((address_space(3))) void*)lds, 16, 0, 0);
}

#define BARRIER() asm volatile("s_barrier" ::: "memory")
#define WAITV(n)  asm volatile("s_waitcnt vmcnt(" #n ")" ::: "memory")
#define LGKM0()   asm volatile("s_waitcnt lgkmcnt(0)" ::: "memory")
#define mfma64(a, b, c) __builtin_amdgcn_mfma_i32_16x16x64_i8(a, b, c, 0, 0, 0)

__global__ __launch_bounds__(256, 2) void gemm_i8(const int8_t* __restrict__ A,
                                                  const int8_t* __restrict__ B,
                                                  const float* __restrict__ sx,
                                                  const float* __restrict__ sw,
                                                  float* __restrict__ C) {
    // dbuf: A 128x128 B (16 KB) x2 + B 128x128 B (16 KB) x2 = 64 KiB
    __shared__ int8_t sA[2][128 * 128];
    __shared__ int8_t sB[2][128 * 128];

    const int tid  = threadIdx.x;
    const int wave = tid >> 6;
    const int lane = tid & 63;
    const int wm = wave >> 1;       // 0..1 (M split)
    const int wn = wave & 1;        // 0..1 (N split)
    const int r4 = lane & 15;
    const int q  = lane >> 4;

    // XCD-aware bijective swizzle: 1024 blocks = 8 XCDs x 128 contiguous
    const int bid = blockIdx.x;
    const int lid = (bid & 7) * 128 + (bid >> 3);
    const int m0 = (lid & 31) * 128;
    const int n0 = (lid >> 5) * 128;

    i32x4 acc[4][4] = {};           // [m][n] -> 64 acc regs
    i32x4 aF[2][4];                 // [ks][m]  A(t), held all tile
    i32x4 bFa[2][2], bFb[2][2];     // [ks][nn] B group 0 / group 1

    // ---- staging map: load l in 0..3: chunk = l*256 + tid; row = chunk>>3
    // (= l*32 + tid>>3), slot = chunk&7, logical chunk c = slot ^ (row&7).
    // (row&7 invariant over l: 32 == 0 mod 8.)
    const int rowS = tid >> 3;                      // 0..31
    const int cS   = (tid & 7) ^ (rowS & 7);
    const size_t rs32 = (size_t)32 * K_DIM;
    const int8_t* gA = A + (size_t)(m0 + rowS) * K_DIM + cS * 16;
    const int8_t* gB = B + (size_t)(n0 + rowS) * K_DIM + cS * 16;
    const int ldsW = wave * 1024;   // + l*4096 per load (wave-uniform)

#define STAGE_A(buf, koff)                                                \
    do {                                                                  \
        async_copy16(&sA[buf][ldsW],         gA + (koff));                \
        async_copy16(&sA[buf][4096 + ldsW],  gA + rs32 + (koff));         \
        async_copy16(&sA[buf][8192 + ldsW],  gA + 2 * rs32 + (koff));     \
        async_copy16(&sA[buf][12288 + ldsW], gA + 3 * rs32 + (koff));     \
    } while (0)
#define STAGE_B(buf, koff)                                                \
    do {                                                                  \
        async_copy16(&sB[buf][ldsW],         gB + (koff));                \
        async_copy16(&sB[buf][4096 + ldsW],  gB + rs32 + (koff));         \
        async_copy16(&sB[buf][8192 + ldsW],  gB + 2 * rs32 + (koff));     \
        async_copy16(&sB[buf][12288 + ldsW], gB + 3 * rs32 + (koff));     \
    } while (0)

    // ---- fragment LDS base offsets (same swizzle family as R5: row stride
    // 128 B, slot = (ks*4+q) ^ (r4&7); frag index adds m*2048 / n*2048) ----
    int aOffB[2], bOffB[2];
#pragma unroll
    for (int ks = 0; ks < 2; ++ks) {
        const int sl = (((ks * 4 + q) ^ (r4 & 7)) * 16);
        aOffB[ks] = (wm * 64 + r4) * 128 + sl;
        bOffB[ks] = (wn * 64 + r4) * 128 + sl;
    }

#define RD_A(buf, ks, m) (*(const i32x4*)&sA[buf][aOffB[ks] + (m) * 2048])
#define RD_B(buf, ks, n) (*(const i32x4*)&sB[buf][bOffB[ks] + (n) * 2048])

// Region 1: 16 MFMA on B group 0 (k0 sweep, k1 sweep); weave group 1 <- p.
#define MMA_R1(p)                                                         \
    do {                                                                  \
        _Pragma("unroll") for (int m = 0; m < 4; ++m)                     \
        _Pragma("unroll") for (int nn = 0; nn < 2; ++nn)                  \
            acc[m][nn] = mfma64(aF[0][m], bFa[0][nn], acc[m][nn]);        \
        bFb[0][0] = RD_B(p, 0, 2);                                        \
        bFb[0][1] = RD_B(p, 0, 3);                                        \
        _Pragma("unroll") for (int m = 0; m < 4; ++m)                     \
        _Pragma("unroll") for (int nn = 0; nn < 2; ++nn)                  \
            acc[m][nn] = mfma64(aF[1][m], bFa[1][nn], acc[m][nn]);        \
        bFb[1][0] = RD_B(p, 1, 2);                                        \
        bFb[1][1] = RD_B(p, 1, 3);                                        \
    } while (0)

// Region 2: 16 MFMA on B group 1; weave next tile's A + B group 0 <- np.
#define MMA_R2(np)                                                        \
    do {                                                                  \
        _Pragma("unroll") for (int m = 0; m < 4; ++m)                     \
        _Pragma("unroll") for (int nn = 0; nn < 2; ++nn)                  \
            acc[m][2+nn] = mfma64(aF[0][m], bFb[0][nn], acc[m][2+nn]);    \
        _Pragma("unroll") for (int m = 0; m < 4; ++m)                     \
            aF[0][m] = RD_A(np, 0, m);                                    \
        bFa[0][0] = RD_B(np, 0, 0);                                       \
        bFa[0][1] = RD_B(np, 0, 1);                                       \
        _Pragma("unroll") for (int m = 0; m < 4; ++m)                     \
        _Pragma("unroll") for (int nn = 0; nn < 2; ++nn)                  \
            acc[m][2+nn] = mfma64(aF[1][m], bFb[1][nn], acc[m][2+nn]);    \
        _Pragma("unroll") for (int m = 0; m < 4; ++m)                     \
            aF[1][m] = RD_A(np, 1, m);                                    \
        bFa[1][0] = RD_B(np, 1, 0);                                       \
        bFa[1][1] = RD_B(np, 1, 1);                                       \
    } while (0)

// Final region 2: no weaves.
#define MMA_R2_END()                                                      \
    do {                                                                  \
        _Pragma("unroll") for (int m = 0; m < 4; ++m)                     \
        _Pragma("unroll") for (int nn = 0; nn < 2; ++nn)                  \
            acc[m][2+nn] = mfma64(aF[0][m], bFb[0][nn], acc[m][2+nn]);    \
        _Pragma("unroll") for (int m = 0; m < 4; ++m)                     \
        _Pragma("unroll") for (int nn = 0; nn < 2; ++nn)                  \
            acc[m][2+nn] = mfma64(aF[1][m], bFb[1][nn], acc[m][2+nn]);    \
    } while (0)

// One tile: 32 MFMA, 2 barriers, stages {B(t+1) -> buf p^1, A(t+2) -> buf p}.
#define TILE(p, koB, koA)                                                 \
    do {                                                                  \
        STAGE_B((p) ^ 1, koB);                                            \
        STAGE_A(p, koA);                                                  \
        MMA_R1(p);                                                        \
        WAITV(4); BARRIER();                                              \
        MMA_R2((p) ^ 1);                                                  \
        BARRIER();                                                        \
    } while (0)

    // ---- prologue: A(0),B(0) -> buf0; A(1) -> buf1; preload frags ----
    STAGE_A(0, 0);
    STAGE_B(0, 0);
    STAGE_A(1, BK);
    WAITV(4);                 // A(0),B(0) retired; A(1) in flight
    BARRIER();
#pragma unroll
    for (int ks = 0; ks < 2; ++ks) {
#pragma unroll
        for (int m = 0; m < 4; ++m) aF[ks][m] = RD_A(0, ks, m);
        bFa[ks][0] = RD_B(0, ks, 0);
        bFa[ks][1] = RD_B(0, ks, 1);
    }
    LGKM0();                  // preload in regs before tile0 overwrites A(0)
    BARRIER();

#pragma unroll 1
    for (int i = 0; i < 15; ++i) {          // tiles 0..29
        TILE(0, (2 * i + 1) * BK, (2 * i + 2) * BK);
        TILE(1, (2 * i + 2) * BK, (2 * i + 3) * BK);
    }

    // ---- tile 30 (p=0): stage only B(31); drain fully at W1 ----
    STAGE_B(1, 31 * BK);
    MMA_R1(0);
    WAITV(0); BARRIER();      // A(31), B(31) retired
    MMA_R2(1);                // weave aF <- A(31), bFa <- B(31) grp0
    BARRIER();
    // ---- tile 31 (p=1): no stages ----
    MMA_R1(1);                // weave bFb <- B(31) grp1
    MMA_R2_END();

    // ---- C write: C/D layout col = lane&15, row = (lane>>4)*4 + reg ----
#pragma unroll
    for (int m = 0; m < 4; ++m) {
        const int rbase = m0 + wm * 64 + m * 16 + q * 4;
        const float4 s4 = *(const float4*)&sx[rbase];
#pragma unroll
        for (int n = 0; n < 4; ++n) {
            const int col = n0 + wn * 64 + n * 16 + r4;
            const float swc = sw[col];
            float* cp = C + (size_t)rbase * N_DIM + col;
            cp[0 * N_DIM] = (float)acc[m][n][0] * s4.x * swc;
            cp[1 * N_DIM] = (float)acc[m][n][1] * s4.y * swc;
            cp[2 * N_DIM] = (float)acc[m][n][2] * s4.z * swc;
            cp[3 * N_DIM] = (float)acc[m][n][3] * s4.w * swc;
        }
    }
#undef STAGE_A
#undef STAGE_B
#undef RD_A
#undef RD_B
#undef MMA_R1
#undef MMA_R2
#undef MMA_R2_END
#undef TILE
}

// ---------------------------------------------------------------------------
// Launch: ws usage = 16.7 MB xq + 16.7 MB wq + 32 KB scales.
// ---------------------------------------------------------------------------
extern "C" void kernel_launch(void* const* d_in, const int* in_sizes, int n_in,
                              void* d_out, int out_size, void* d_ws, size_t ws_size,
                              hipStream_t stream) {
    const float* x      = (const float*)d_in[0];
    const int*   packed = (const int*)d_in[1];
    const float* d      = (const float*)d_in[2];
    const float* dmin   = (const float*)d_in[3];
    const int*   scales = (const int*)d_in[4];
    const int*   mins   = (const int*)d_in[5];
    float* out = (float*)d_out;

    int8_t* xq = (int8_t*)d_ws;                               // 16.7 MB
    int8_t* wq = xq + (size_t)M_DIM * K_DIM;                  // 16.7 MB
    float*  sx = (float*)(wq + (size_t)N_DIM * K_DIM);        // 16 KB
    float*  sw = sx + M_DIM;                                  // 16 KB

    quant_xw<<<2048, 256, 0, stream>>>(x, packed, d, dmin, scales, mins,
                                       xq, sx, wq, sw);
    gemm_i8<<<1024, 256, 0, stream>>>(xq, wq, sx, sw, out);
}